// Round 1
// baseline (104.675 us; speedup 1.0000x reference)
//
#include <hip/hip_runtime.h>
#include <math.h>

#define NPTS 4096
#define NB 4
#define EPSF 1e-6f

// ---------------- K0: per-batch setup -----------------------------------
// One block per batch (256 threads). Computes means, gravity-align R,
// t_center, then writes:
//   p4[n]  = (src_init.x,y,z, ||src_init||^2)
//   q4[m]  = (tgt.x,y,z, ||tgt||^2)
//   snr4[n]= (R@src_n, 0)
//   tn4[m] = (tgt_n, 0)
__global__ void k0_setup(const float* __restrict__ src, const float* __restrict__ tgt,
                         const float* __restrict__ src_n, const float* __restrict__ tgt_n,
                         const float* __restrict__ g_p, const float* __restrict__ g_q,
                         float4* __restrict__ p4, float4* __restrict__ q4,
                         float4* __restrict__ snr4, float4* __restrict__ tn4) {
    const int b = blockIdx.x;
    const int tid = threadIdx.x;
    const float* S  = src   + (size_t)b * 3 * NPTS;
    const float* T  = tgt   + (size_t)b * 3 * NPTS;
    const float* SN = src_n + (size_t)b * 3 * NPTS;
    const float* TN = tgt_n + (size_t)b * 3 * NPTS;

    float acc[6] = {0.f, 0.f, 0.f, 0.f, 0.f, 0.f};
    for (int n = tid; n < NPTS; n += 256) {
        acc[0] += S[n]; acc[1] += S[NPTS + n]; acc[2] += S[2 * NPTS + n];
        acc[3] += T[n]; acc[4] += T[NPTS + n]; acc[5] += T[2 * NPTS + n];
    }
    __shared__ float red[256];
    __shared__ float sums[6];
    for (int c = 0; c < 6; ++c) {
        red[tid] = acc[c];
        __syncthreads();
        for (int s = 128; s > 0; s >>= 1) {
            if (tid < s) red[tid] += red[tid + s];
            __syncthreads();
        }
        if (tid == 0) sums[c] = red[0];
        __syncthreads();
    }

    __shared__ float Rg[9], tc[3];
    if (tid == 0) {
        // gravity_align(g_p[b], g_q[b]) exactly per reference
        float gpx = g_p[3 * b + 0], gpy = g_p[3 * b + 1], gpz = g_p[3 * b + 2];
        float gqx = g_q[3 * b + 0], gqy = g_q[3 * b + 1], gqz = g_q[3 * b + 2];
        float nu = sqrtf(gpx * gpx + gpy * gpy + gpz * gpz);
        float du = fmaxf(nu, EPSF);
        float ux = gpx / du, uy = gpy / du, uz = gpz / du;
        float nv = sqrtf(gqx * gqx + gqy * gqy + gqz * gqz);
        float dv = fmaxf(nv, EPSF);
        float vx = gqx / dv, vy = gqy / dv, vz = gqz / dv;

        float ax = uy * vz - uz * vy;
        float ay = uz * vx - ux * vz;
        float az = ux * vy - uy * vx;
        float an = sqrtf(ax * ax + ay * ay + az * az);
        float dot = ux * vx + uy * vy + uz * vz;
        dot = fminf(1.0f, fmaxf(-1.0f, dot));
        bool parallel = (an < 1e-6f);

        float kx = ax / (an + EPSF), ky = ay / (an + EPSF), kz = az / (an + EPSF);
        float theta = acosf(dot);
        float st = sinf(theta), ct = cosf(theta);

        float K[9] = {0.f, -kz, ky,  kz, 0.f, -kx,  -ky, kx, 0.f};
        float KK[9];
        for (int i = 0; i < 3; ++i)
            for (int j = 0; j < 3; ++j) {
                float s2 = 0.f;
                for (int l = 0; l < 3; ++l) s2 += K[i * 3 + l] * K[l * 3 + j];
                KK[i * 3 + j] = s2;
            }
        float R[9];
        for (int i = 0; i < 9; ++i) {
            float I = (i == 0 || i == 4 || i == 8) ? 1.f : 0.f;
            R[i] = I + st * K[i] + (1.f - ct) * KK[i];
        }
        if (parallel) {
            if (dot < 0.f) {
                float bx, by, bz;
                if (fabsf(ux) < 0.9f) { bx = 1.f; by = 0.f; bz = 0.f; }
                else                  { bx = 0.f; by = 1.f; bz = 0.f; }
                float cx = uy * bz - uz * by;
                float cy = uz * bx - ux * bz;
                float cz = ux * by - uy * bx;
                float cn = sqrtf(cx * cx + cy * cy + cz * cz);
                float cd = fmaxf(cn, EPSF);
                cx /= cd; cy /= cd; cz /= cd;
                float K2[9] = {0.f, -cz, cy,  cz, 0.f, -cx,  -cy, cx, 0.f};
                float K2K2[9];
                for (int i = 0; i < 3; ++i)
                    for (int j = 0; j < 3; ++j) {
                        float s2 = 0.f;
                        for (int l = 0; l < 3; ++l) s2 += K2[i * 3 + l] * K2[l * 3 + j];
                        K2K2[i * 3 + j] = s2;
                    }
                for (int i = 0; i < 9; ++i) {
                    float I = (i == 0 || i == 4 || i == 8) ? 1.f : 0.f;
                    R[i] = I + 2.f * K2K2[i];
                }
            } else if (dot > 0.f) {
                for (int i = 0; i < 9; ++i) R[i] = (i == 0 || i == 4 || i == 8) ? 1.f : 0.f;
            }
        }
        float ms0 = sums[0] / (float)NPTS, ms1 = sums[1] / (float)NPTS, ms2 = sums[2] / (float)NPTS;
        float mt0 = sums[3] / (float)NPTS, mt1 = sums[4] / (float)NPTS, mt2 = sums[5] / (float)NPTS;
        for (int i = 0; i < 9; ++i) Rg[i] = R[i];
        tc[0] = mt0 - (R[0] * ms0 + R[1] * ms1 + R[2] * ms2);
        tc[1] = mt1 - (R[3] * ms0 + R[4] * ms1 + R[5] * ms2);
        tc[2] = mt2 - (R[6] * ms0 + R[7] * ms1 + R[8] * ms2);
    }
    __syncthreads();

    const float R0 = Rg[0], R1 = Rg[1], R2 = Rg[2];
    const float R3 = Rg[3], R4 = Rg[4], R5 = Rg[5];
    const float R6 = Rg[6], R7 = Rg[7], R8 = Rg[8];
    const float t0 = tc[0], t1 = tc[1], t2 = tc[2];

    for (int n = tid; n < NPTS; n += 256) {
        float s0 = S[n], s1 = S[NPTS + n], s2 = S[2 * NPTS + n];
        float p0 = R0 * s0 + R1 * s1 + R2 * s2 + t0;
        float p1 = R3 * s0 + R4 * s1 + R5 * s2 + t1;
        float p2 = R6 * s0 + R7 * s1 + R8 * s2 + t2;
        p4[b * NPTS + n] = make_float4(p0, p1, p2, p0 * p0 + p1 * p1 + p2 * p2);

        float q0 = T[n], q1 = T[NPTS + n], q2 = T[2 * NPTS + n];
        q4[b * NPTS + n] = make_float4(q0, q1, q2, q0 * q0 + q1 * q1 + q2 * q2);

        float a0 = SN[n], a1 = SN[NPTS + n], a2 = SN[2 * NPTS + n];
        snr4[b * NPTS + n] = make_float4(R0 * a0 + R1 * a1 + R2 * a2,
                                         R3 * a0 + R4 * a1 + R5 * a2,
                                         R6 * a0 + R7 * a1 + R8 * a2, 0.f);
        float c0 = TN[n], c1 = TN[NPTS + n], c2 = TN[2 * NPTS + n];
        tn4[b * NPTS + n] = make_float4(c0, c1, c2, 0.f);
    }
}

// ---------------- K1: nearest neighbor (both directions) ----------------
// grid (64, B, 2); 256 threads. z=0: for each src point, min over tgt
// (axis=2). z=1: for each tgt point, min over src (axis=1).
// Each block: 64 "own" points x full 4096 "other" points staged in LDS.
// Wave lanes share the same staged point each iteration -> LDS broadcast.
__global__ void k1_nn(const float4* __restrict__ p4, const float4* __restrict__ q4,
                      float* __restrict__ nnp, int* __restrict__ idxp,
                      float* __restrict__ nnq, int* __restrict__ idxq) {
    const int b = blockIdx.y;
    const int z = blockIdx.z;
    const float4* own = z ? q4 : p4;
    const float4* oth = z ? p4 : q4;
    float* nn = z ? nnq : nnp;
    int* idx = z ? idxq : idxp;

    __shared__ float4 stage[NPTS];  // 64 KB
    const int tid = threadIdx.x;
    for (int i = tid; i < NPTS; i += 256) stage[i] = oth[b * NPTS + i];

    const int nl = tid & 63;
    const int stripe = tid >> 6;
    const int n = blockIdx.x * 64 + nl;
    const float4 p = own[b * NPTS + n];
    __syncthreads();

    const int m0 = stripe * 1024;
    float best = 3.4e38f;
    int bi = m0;
    #pragma unroll 4
    for (int m = m0; m < m0 + 1024; ++m) {
        float4 q = stage[m];
        float t = fmaf(p.x, q.x, fmaf(p.y, q.y, p.z * q.z));
        float d = (p.w - 2.0f * t) + q.w;
        if (d < best) { best = d; bi = m; }
    }
    __syncthreads();

    // reuse stage LDS for the 4-stripe combine
    float* combd = (float*)stage;
    int* combi = (int*)(combd + 256);
    combd[tid] = best;
    combi[tid] = bi;
    __syncthreads();
    if (stripe == 0) {
        for (int s2 = 1; s2 < 4; ++s2) {
            float d2 = combd[s2 * 64 + nl];
            int i2 = combi[s2 * 64 + nl];
            if (d2 < best) { best = d2; bi = i2; }  // strict <: lower stripe wins ties
        }
        nn[b * NPTS + n] = sqrtf(fmaxf(best, 0.f) + EPSF);
        idx[b * NPTS + n] = bi;
    }
}

// ---------------- K2: lower median -> tau -------------------------------
// grid (B, 2); 1024 threads. Bitonic sort 4096 floats in LDS, exact
// lower median = sorted[2047]; tau = 3 * median.
__global__ void k2_tau(const float* __restrict__ nnp, const float* __restrict__ nnq,
                       float* __restrict__ tau) {
    const int b = blockIdx.x;
    const int side = blockIdx.y;
    const float* a = side ? nnq : nnp;
    __shared__ float s[NPTS];
    const int tid = threadIdx.x;
    for (int i = tid; i < NPTS; i += 1024) s[i] = a[b * NPTS + i];
    __syncthreads();
    for (int k = 2; k <= NPTS; k <<= 1) {
        for (int j = k >> 1; j > 0; j >>= 1) {
            for (int i = tid; i < NPTS; i += 1024) {
                int ixj = i ^ j;
                if (ixj > i) {
                    float x = s[i], y = s[ixj];
                    bool up = ((i & k) == 0);
                    if ((x > y) == up) { s[i] = y; s[ixj] = x; }
                }
            }
            __syncthreads();
        }
    }
    if (tid == 0) tau[side * NB + b] = 3.0f * s[2047];
}

// ---------------- K3: incidence weights ---------------------------------
// grid (16, B, 2); 256 threads.
__global__ void k3_w(const float4* __restrict__ snr4, const float4* __restrict__ tn4,
                     const int* __restrict__ idxp, const int* __restrict__ idxq,
                     const float* __restrict__ nnp, const float* __restrict__ nnq,
                     const float* __restrict__ tau,
                     const float* __restrict__ g_q, const float* __restrict__ k_p,
                     const float* __restrict__ k_q, float* __restrict__ out) {
    const int b = blockIdx.y;
    const int z = blockIdx.z;
    const int n = blockIdx.x * 256 + threadIdx.x;
    const float gx = g_q[3 * b + 0], gy = g_q[3 * b + 1], gz = g_q[3 * b + 2];
    const float kp = k_p[b], kq = k_q[b];
    const float keff = kp * kq / (kp + kq + EPSF);

    if (z == 0) {
        float4 sn = snr4[b * NPTS + n];
        float inc = sn.x * gx + sn.y * gy + sn.z * gz;
        int j = idxp[b * NPTS + n];
        float4 tn = tn4[b * NPTS + j];
        float incr = tn.x * gx + tn.y * gy + tn.z * gz;
        float diff = inc - incr;
        float arg = 9.0f - keff * diff * diff;
        float sig = 1.f / (1.f + expf(-arg));
        float geom = (nnp[b * NPTS + n] <= tau[b]) ? 1.f : 0.f;
        out[b * NPTS + n] = sig * geom;
    } else {
        float4 tn = tn4[b * NPTS + n];
        float inc = tn.x * gx + tn.y * gy + tn.z * gz;
        int j = idxq[b * NPTS + n];
        float4 sn = snr4[b * NPTS + j];
        float incr = sn.x * gx + sn.y * gy + sn.z * gz;
        float diff = inc - incr;
        float arg = 9.0f - keff * diff * diff;
        float sig = 1.f / (1.f + expf(-arg));
        float geom = (nnq[b * NPTS + n] <= tau[NB + b]) ? 1.f : 0.f;
        out[NB * NPTS + b * NPTS + n] = sig * geom;
    }
}

extern "C" void kernel_launch(void* const* d_in, const int* in_sizes, int n_in,
                              void* d_out, int out_size, void* d_ws, size_t ws_size,
                              hipStream_t stream) {
    const float* src   = (const float*)d_in[0];
    const float* tgt   = (const float*)d_in[1];
    const float* src_n = (const float*)d_in[2];
    const float* tgt_n = (const float*)d_in[3];
    const float* g_p   = (const float*)d_in[4];
    const float* k_p   = (const float*)d_in[5];
    const float* g_q   = (const float*)d_in[6];
    const float* k_q   = (const float*)d_in[7];
    float* out = (float*)d_out;

    const int BN = NB * NPTS;
    float4* p4   = (float4*)d_ws;
    float4* q4   = p4 + BN;
    float4* snr4 = q4 + BN;
    float4* tn4  = snr4 + BN;
    float* nnp = (float*)(tn4 + BN);
    float* nnq = nnp + BN;
    int* idxp = (int*)(nnq + BN);
    int* idxq = idxp + BN;
    float* tau = (float*)(idxq + BN);  // 2*NB floats

    k0_setup<<<dim3(NB), dim3(256), 0, stream>>>(src, tgt, src_n, tgt_n, g_p, g_q,
                                                 p4, q4, snr4, tn4);
    k1_nn<<<dim3(NPTS / 64, NB, 2), dim3(256), 0, stream>>>(p4, q4, nnp, idxp, nnq, idxq);
    k2_tau<<<dim3(NB, 2), dim3(1024), 0, stream>>>(nnp, nnq, tau);
    k3_w<<<dim3(NPTS / 256, NB, 2), dim3(256), 0, stream>>>(snr4, tn4, idxp, idxq,
                                                            nnp, nnq, tau,
                                                            g_q, k_p, k_q, out);
}

// Round 2
// 78.684 us; speedup vs baseline: 1.3303x; 1.3303x over previous
//
#include <hip/hip_runtime.h>
#include <math.h>

#define NPTS 4096
#define NB 4
#define EPSF 1e-6f

// ---------------- K0: per-batch setup -----------------------------------
// One block per batch (256 threads). Computes means, gravity-align R,
// t_center, then writes:
//   p4[n]  = (src_init.x,y,z, ||src_init||^2)
//   q4[m]  = (tgt.x,y,z, ||tgt||^2)
//   snr4[n]= (R@src_n, 0)
//   tn4[m] = (tgt_n, 0)
__global__ void k0_setup(const float* __restrict__ src, const float* __restrict__ tgt,
                         const float* __restrict__ src_n, const float* __restrict__ tgt_n,
                         const float* __restrict__ g_p, const float* __restrict__ g_q,
                         float4* __restrict__ p4, float4* __restrict__ q4,
                         float4* __restrict__ snr4, float4* __restrict__ tn4) {
    const int b = blockIdx.x;
    const int tid = threadIdx.x;
    const float* S  = src   + (size_t)b * 3 * NPTS;
    const float* T  = tgt   + (size_t)b * 3 * NPTS;
    const float* SN = src_n + (size_t)b * 3 * NPTS;
    const float* TN = tgt_n + (size_t)b * 3 * NPTS;

    float acc[6] = {0.f, 0.f, 0.f, 0.f, 0.f, 0.f};
    for (int n = tid; n < NPTS; n += 256) {
        acc[0] += S[n]; acc[1] += S[NPTS + n]; acc[2] += S[2 * NPTS + n];
        acc[3] += T[n]; acc[4] += T[NPTS + n]; acc[5] += T[2 * NPTS + n];
    }
    __shared__ float red[256];
    __shared__ float sums[6];
    for (int c = 0; c < 6; ++c) {
        red[tid] = acc[c];
        __syncthreads();
        for (int s = 128; s > 0; s >>= 1) {
            if (tid < s) red[tid] += red[tid + s];
            __syncthreads();
        }
        if (tid == 0) sums[c] = red[0];
        __syncthreads();
    }

    __shared__ float Rg[9], tc[3];
    if (tid == 0) {
        // gravity_align(g_p[b], g_q[b]) exactly per reference
        float gpx = g_p[3 * b + 0], gpy = g_p[3 * b + 1], gpz = g_p[3 * b + 2];
        float gqx = g_q[3 * b + 0], gqy = g_q[3 * b + 1], gqz = g_q[3 * b + 2];
        float nu = sqrtf(gpx * gpx + gpy * gpy + gpz * gpz);
        float du = fmaxf(nu, EPSF);
        float ux = gpx / du, uy = gpy / du, uz = gpz / du;
        float nv = sqrtf(gqx * gqx + gqy * gqy + gqz * gqz);
        float dv = fmaxf(nv, EPSF);
        float vx = gqx / dv, vy = gqy / dv, vz = gqz / dv;

        float ax = uy * vz - uz * vy;
        float ay = uz * vx - ux * vz;
        float az = ux * vy - uy * vx;
        float an = sqrtf(ax * ax + ay * ay + az * az);
        float dot = ux * vx + uy * vy + uz * vz;
        dot = fminf(1.0f, fmaxf(-1.0f, dot));
        bool parallel = (an < 1e-6f);

        float kx = ax / (an + EPSF), ky = ay / (an + EPSF), kz = az / (an + EPSF);
        float theta = acosf(dot);
        float st = sinf(theta), ct = cosf(theta);

        float K[9] = {0.f, -kz, ky,  kz, 0.f, -kx,  -ky, kx, 0.f};
        float KK[9];
        for (int i = 0; i < 3; ++i)
            for (int j = 0; j < 3; ++j) {
                float s2 = 0.f;
                for (int l = 0; l < 3; ++l) s2 += K[i * 3 + l] * K[l * 3 + j];
                KK[i * 3 + j] = s2;
            }
        float R[9];
        for (int i = 0; i < 9; ++i) {
            float I = (i == 0 || i == 4 || i == 8) ? 1.f : 0.f;
            R[i] = I + st * K[i] + (1.f - ct) * KK[i];
        }
        if (parallel) {
            if (dot < 0.f) {
                float bx, by, bz;
                if (fabsf(ux) < 0.9f) { bx = 1.f; by = 0.f; bz = 0.f; }
                else                  { bx = 0.f; by = 1.f; bz = 0.f; }
                float cx = uy * bz - uz * by;
                float cy = uz * bx - ux * bz;
                float cz = ux * by - uy * bx;
                float cn = sqrtf(cx * cx + cy * cy + cz * cz);
                float cd = fmaxf(cn, EPSF);
                cx /= cd; cy /= cd; cz /= cd;
                float K2[9] = {0.f, -cz, cy,  cz, 0.f, -cx,  -cy, cx, 0.f};
                float K2K2[9];
                for (int i = 0; i < 3; ++i)
                    for (int j = 0; j < 3; ++j) {
                        float s2 = 0.f;
                        for (int l = 0; l < 3; ++l) s2 += K2[i * 3 + l] * K2[l * 3 + j];
                        K2K2[i * 3 + j] = s2;
                    }
                for (int i = 0; i < 9; ++i) {
                    float I = (i == 0 || i == 4 || i == 8) ? 1.f : 0.f;
                    R[i] = I + 2.f * K2K2[i];
                }
            } else if (dot > 0.f) {
                for (int i = 0; i < 9; ++i) R[i] = (i == 0 || i == 4 || i == 8) ? 1.f : 0.f;
            }
        }
        float ms0 = sums[0] / (float)NPTS, ms1 = sums[1] / (float)NPTS, ms2 = sums[2] / (float)NPTS;
        float mt0 = sums[3] / (float)NPTS, mt1 = sums[4] / (float)NPTS, mt2 = sums[5] / (float)NPTS;
        for (int i = 0; i < 9; ++i) Rg[i] = R[i];
        tc[0] = mt0 - (R[0] * ms0 + R[1] * ms1 + R[2] * ms2);
        tc[1] = mt1 - (R[3] * ms0 + R[4] * ms1 + R[5] * ms2);
        tc[2] = mt2 - (R[6] * ms0 + R[7] * ms1 + R[8] * ms2);
    }
    __syncthreads();

    const float R0 = Rg[0], R1 = Rg[1], R2 = Rg[2];
    const float R3 = Rg[3], R4 = Rg[4], R5 = Rg[5];
    const float R6 = Rg[6], R7 = Rg[7], R8 = Rg[8];
    const float t0 = tc[0], t1 = tc[1], t2 = tc[2];

    for (int n = tid; n < NPTS; n += 256) {
        float s0 = S[n], s1 = S[NPTS + n], s2 = S[2 * NPTS + n];
        float p0 = R0 * s0 + R1 * s1 + R2 * s2 + t0;
        float p1 = R3 * s0 + R4 * s1 + R5 * s2 + t1;
        float p2 = R6 * s0 + R7 * s1 + R8 * s2 + t2;
        p4[b * NPTS + n] = make_float4(p0, p1, p2, p0 * p0 + p1 * p1 + p2 * p2);

        float q0 = T[n], q1 = T[NPTS + n], q2 = T[2 * NPTS + n];
        q4[b * NPTS + n] = make_float4(q0, q1, q2, q0 * q0 + q1 * q1 + q2 * q2);

        float a0 = SN[n], a1 = SN[NPTS + n], a2 = SN[2 * NPTS + n];
        snr4[b * NPTS + n] = make_float4(R0 * a0 + R1 * a1 + R2 * a2,
                                         R3 * a0 + R4 * a1 + R5 * a2,
                                         R6 * a0 + R7 * a1 + R8 * a2, 0.f);
        float c0 = TN[n], c1 = TN[NPTS + n], c2 = TN[2 * NPTS + n];
        tn4[b * NPTS + n] = make_float4(c0, c1, c2, 0.f);
    }
}

// ---------------- K1: nearest neighbor (both directions) ----------------
// grid (64, B, 2); 256 threads. z=0: for each src point, min over tgt
// (axis=2). z=1: for each tgt point, min over src (axis=1).
// Each block: 64 "own" points x full 4096 "other" points staged in LDS.
// Wave lanes share the same staged point each iteration -> LDS broadcast.
// NOTE: distance arithmetic intentionally matches np reference bitwise
// (absmax 0.0 in R0) — do not refactor into fused -2p form.
__global__ void k1_nn(const float4* __restrict__ p4, const float4* __restrict__ q4,
                      float* __restrict__ nnp, int* __restrict__ idxp,
                      float* __restrict__ nnq, int* __restrict__ idxq) {
    const int b = blockIdx.y;
    const int z = blockIdx.z;
    const float4* own = z ? q4 : p4;
    const float4* oth = z ? p4 : q4;
    float* nn = z ? nnq : nnp;
    int* idx = z ? idxq : idxp;

    __shared__ float4 stage[NPTS];  // 64 KB
    const int tid = threadIdx.x;
    for (int i = tid; i < NPTS; i += 256) stage[i] = oth[b * NPTS + i];

    const int nl = tid & 63;
    const int stripe = tid >> 6;
    const int n = blockIdx.x * 64 + nl;
    const float4 p = own[b * NPTS + n];
    __syncthreads();

    const int m0 = stripe * 1024;
    float best = 3.4e38f;
    int bi = m0;
    #pragma unroll 4
    for (int m = m0; m < m0 + 1024; ++m) {
        float4 q = stage[m];
        float t = fmaf(p.x, q.x, fmaf(p.y, q.y, p.z * q.z));
        float d = (p.w - 2.0f * t) + q.w;
        if (d < best) { best = d; bi = m; }
    }
    __syncthreads();

    // reuse stage LDS for the 4-stripe combine
    float* combd = (float*)stage;
    int* combi = (int*)(combd + 256);
    combd[tid] = best;
    combi[tid] = bi;
    __syncthreads();
    if (stripe == 0) {
        for (int s2 = 1; s2 < 4; ++s2) {
            float d2 = combd[s2 * 64 + nl];
            int i2 = combi[s2 * 64 + nl];
            if (d2 < best) { best = d2; bi = i2; }  // strict <: lower stripe wins ties
        }
        nn[b * NPTS + n] = sqrtf(fmaxf(best, 0.f) + EPSF);
        idx[b * NPTS + n] = bi;
    }
}

// ---------------- K2: lower median -> tau (exact rank-count select) -----
// grid (64, B, 2); 256 threads. For each element x of the 4096, count
// less = #{o < x}, eq = #{o == x}. x is sorted[2047] iff
// less <= 2047 < less+eq. All winners share the same bit pattern
// (values are sqrt(...)>0, no +-0), so racing writes are value-identical.
__global__ void k2_tau(const float* __restrict__ nnp, const float* __restrict__ nnq,
                       float* __restrict__ tau) {
    const int b = blockIdx.y;
    const int side = blockIdx.z;
    const float* a = (side ? nnq : nnp) + b * NPTS;
    __shared__ float stage[NPTS];  // 16 KB
    const int tid = threadIdx.x;
    for (int i = tid; i < NPTS; i += 256) stage[i] = a[i];

    const int nl = tid & 63;
    const int stripe = tid >> 6;
    const int n = blockIdx.x * 64 + nl;
    __syncthreads();

    const float x = stage[n];
    int less = 0, eq = 0;
    const int m0 = stripe * 1024;
    #pragma unroll 8
    for (int m = m0; m < m0 + 1024; ++m) {
        float o = stage[m];  // broadcast read, conflict-free
        less += (o < x) ? 1 : 0;
        eq   += (o == x) ? 1 : 0;
    }
    __syncthreads();

    int* cl = (int*)stage;
    int* ce = cl + 256;
    cl[tid] = less;
    ce[tid] = eq;
    __syncthreads();
    if (stripe == 0) {
        for (int s2 = 1; s2 < 4; ++s2) {
            less += cl[s2 * 64 + nl];
            eq   += ce[s2 * 64 + nl];
        }
        if (less <= 2047 && 2047 < less + eq)
            tau[side * NB + b] = 3.0f * x;
    }
}

// ---------------- K3: incidence weights ---------------------------------
// grid (16, B, 2); 256 threads.
__global__ void k3_w(const float4* __restrict__ snr4, const float4* __restrict__ tn4,
                     const int* __restrict__ idxp, const int* __restrict__ idxq,
                     const float* __restrict__ nnp, const float* __restrict__ nnq,
                     const float* __restrict__ tau,
                     const float* __restrict__ g_q, const float* __restrict__ k_p,
                     const float* __restrict__ k_q, float* __restrict__ out) {
    const int b = blockIdx.y;
    const int z = blockIdx.z;
    const int n = blockIdx.x * 256 + threadIdx.x;
    const float gx = g_q[3 * b + 0], gy = g_q[3 * b + 1], gz = g_q[3 * b + 2];
    const float kp = k_p[b], kq = k_q[b];
    const float keff = kp * kq / (kp + kq + EPSF);

    if (z == 0) {
        float4 sn = snr4[b * NPTS + n];
        float inc = sn.x * gx + sn.y * gy + sn.z * gz;
        int j = idxp[b * NPTS + n];
        float4 tn = tn4[b * NPTS + j];
        float incr = tn.x * gx + tn.y * gy + tn.z * gz;
        float diff = inc - incr;
        float arg = 9.0f - keff * diff * diff;
        float sig = 1.f / (1.f + expf(-arg));
        float geom = (nnp[b * NPTS + n] <= tau[b]) ? 1.f : 0.f;
        out[b * NPTS + n] = sig * geom;
    } else {
        float4 tn = tn4[b * NPTS + n];
        float inc = tn.x * gx + tn.y * gy + tn.z * gz;
        int j = idxq[b * NPTS + n];
        float4 sn = snr4[b * NPTS + j];
        float incr = sn.x * gx + sn.y * gy + sn.z * gz;
        float diff = inc - incr;
        float arg = 9.0f - keff * diff * diff;
        float sig = 1.f / (1.f + expf(-arg));
        float geom = (nnq[b * NPTS + n] <= tau[NB + b]) ? 1.f : 0.f;
        out[NB * NPTS + b * NPTS + n] = sig * geom;
    }
}

extern "C" void kernel_launch(void* const* d_in, const int* in_sizes, int n_in,
                              void* d_out, int out_size, void* d_ws, size_t ws_size,
                              hipStream_t stream) {
    const float* src   = (const float*)d_in[0];
    const float* tgt   = (const float*)d_in[1];
    const float* src_n = (const float*)d_in[2];
    const float* tgt_n = (const float*)d_in[3];
    const float* g_p   = (const float*)d_in[4];
    const float* k_p   = (const float*)d_in[5];
    const float* g_q   = (const float*)d_in[6];
    const float* k_q   = (const float*)d_in[7];
    float* out = (float*)d_out;

    const int BN = NB * NPTS;
    float4* p4   = (float4*)d_ws;
    float4* q4   = p4 + BN;
    float4* snr4 = q4 + BN;
    float4* tn4  = snr4 + BN;
    float* nnp = (float*)(tn4 + BN);
    float* nnq = nnp + BN;
    int* idxp = (int*)(nnq + BN);
    int* idxq = idxp + BN;
    float* tau = (float*)(idxq + BN);  // 2*NB floats

    k0_setup<<<dim3(NB), dim3(256), 0, stream>>>(src, tgt, src_n, tgt_n, g_p, g_q,
                                                 p4, q4, snr4, tn4);
    k1_nn<<<dim3(NPTS / 64, NB, 2), dim3(256), 0, stream>>>(p4, q4, nnp, idxp, nnq, idxq);
    k2_tau<<<dim3(NPTS / 64, NB, 2), dim3(256), 0, stream>>>(nnp, nnq, tau);
    k3_w<<<dim3(NPTS / 256, NB, 2), dim3(256), 0, stream>>>(snr4, tn4, idxp, idxq,
                                                            nnp, nnq, tau,
                                                            g_q, k_p, k_q, out);
}

// Round 3
// 61.506 us; speedup vs baseline: 1.7019x; 1.2793x over previous
//
#include <hip/hip_runtime.h>
#include <math.h>

#define NPTS 4096
#define NB 4
#define EPSF 1e-6f

// ---------------- K0a: per-batch means + gravity-align R, t -------------
// One block per batch (256 threads). Writes Rt[b*16 + {0..8:R, 9..11:t}].
__global__ void k0a_rt(const float* __restrict__ src, const float* __restrict__ tgt,
                       const float* __restrict__ g_p, const float* __restrict__ g_q,
                       float* __restrict__ Rt) {
    const int b = blockIdx.x;
    const int tid = threadIdx.x;
    const float* S = src + (size_t)b * 3 * NPTS;
    const float* T = tgt + (size_t)b * 3 * NPTS;

    float acc[6] = {0.f, 0.f, 0.f, 0.f, 0.f, 0.f};
    for (int n = tid; n < NPTS; n += 256) {
        acc[0] += S[n]; acc[1] += S[NPTS + n]; acc[2] += S[2 * NPTS + n];
        acc[3] += T[n]; acc[4] += T[NPTS + n]; acc[5] += T[2 * NPTS + n];
    }
    __shared__ float red[256];
    __shared__ float sums[6];
    for (int c = 0; c < 6; ++c) {
        red[tid] = acc[c];
        __syncthreads();
        for (int s = 128; s > 0; s >>= 1) {
            if (tid < s) red[tid] += red[tid + s];
            __syncthreads();
        }
        if (tid == 0) sums[c] = red[0];
        __syncthreads();
    }

    if (tid == 0) {
        // gravity_align(g_p[b], g_q[b]) exactly per reference
        float gpx = g_p[3 * b + 0], gpy = g_p[3 * b + 1], gpz = g_p[3 * b + 2];
        float gqx = g_q[3 * b + 0], gqy = g_q[3 * b + 1], gqz = g_q[3 * b + 2];
        float nu = sqrtf(gpx * gpx + gpy * gpy + gpz * gpz);
        float du = fmaxf(nu, EPSF);
        float ux = gpx / du, uy = gpy / du, uz = gpz / du;
        float nv = sqrtf(gqx * gqx + gqy * gqy + gqz * gqz);
        float dv = fmaxf(nv, EPSF);
        float vx = gqx / dv, vy = gqy / dv, vz = gqz / dv;

        float ax = uy * vz - uz * vy;
        float ay = uz * vx - ux * vz;
        float az = ux * vy - uy * vx;
        float an = sqrtf(ax * ax + ay * ay + az * az);
        float dot = ux * vx + uy * vy + uz * vz;
        dot = fminf(1.0f, fmaxf(-1.0f, dot));
        bool parallel = (an < 1e-6f);

        float kx = ax / (an + EPSF), ky = ay / (an + EPSF), kz = az / (an + EPSF);
        float theta = acosf(dot);
        float st = sinf(theta), ct = cosf(theta);

        float K[9] = {0.f, -kz, ky,  kz, 0.f, -kx,  -ky, kx, 0.f};
        float KK[9];
        for (int i = 0; i < 3; ++i)
            for (int j = 0; j < 3; ++j) {
                float s2 = 0.f;
                for (int l = 0; l < 3; ++l) s2 += K[i * 3 + l] * K[l * 3 + j];
                KK[i * 3 + j] = s2;
            }
        float R[9];
        for (int i = 0; i < 9; ++i) {
            float I = (i == 0 || i == 4 || i == 8) ? 1.f : 0.f;
            R[i] = I + st * K[i] + (1.f - ct) * KK[i];
        }
        if (parallel) {
            if (dot < 0.f) {
                float bx, by, bz;
                if (fabsf(ux) < 0.9f) { bx = 1.f; by = 0.f; bz = 0.f; }
                else                  { bx = 0.f; by = 1.f; bz = 0.f; }
                float cx = uy * bz - uz * by;
                float cy = uz * bx - ux * bz;
                float cz = ux * by - uy * bx;
                float cn = sqrtf(cx * cx + cy * cy + cz * cz);
                float cd = fmaxf(cn, EPSF);
                cx /= cd; cy /= cd; cz /= cd;
                float K2[9] = {0.f, -cz, cy,  cz, 0.f, -cx,  -cy, cx, 0.f};
                float K2K2[9];
                for (int i = 0; i < 3; ++i)
                    for (int j = 0; j < 3; ++j) {
                        float s2 = 0.f;
                        for (int l = 0; l < 3; ++l) s2 += K2[i * 3 + l] * K2[l * 3 + j];
                        K2K2[i * 3 + j] = s2;
                    }
                for (int i = 0; i < 9; ++i) {
                    float I = (i == 0 || i == 4 || i == 8) ? 1.f : 0.f;
                    R[i] = I + 2.f * K2K2[i];
                }
            } else if (dot > 0.f) {
                for (int i = 0; i < 9; ++i) R[i] = (i == 0 || i == 4 || i == 8) ? 1.f : 0.f;
            }
        }
        float ms0 = sums[0] / (float)NPTS, ms1 = sums[1] / (float)NPTS, ms2 = sums[2] / (float)NPTS;
        float mt0 = sums[3] / (float)NPTS, mt1 = sums[4] / (float)NPTS, mt2 = sums[5] / (float)NPTS;
        for (int i = 0; i < 9; ++i) Rt[b * 16 + i] = R[i];
        Rt[b * 16 + 9]  = mt0 - (R[0] * ms0 + R[1] * ms1 + R[2] * ms2);
        Rt[b * 16 + 10] = mt1 - (R[3] * ms0 + R[4] * ms1 + R[5] * ms2);
        Rt[b * 16 + 11] = mt2 - (R[6] * ms0 + R[7] * ms1 + R[8] * ms2);
    }
}

// ---------------- K0b: transform + pack float4 --------------------------
// grid (8, NB); 256 threads; each thread handles 2 points.
__global__ void k0b_pack(const float* __restrict__ src, const float* __restrict__ tgt,
                         const float* __restrict__ src_n, const float* __restrict__ tgt_n,
                         const float* __restrict__ Rt,
                         float4* __restrict__ p4, float4* __restrict__ q4,
                         float4* __restrict__ snr4, float4* __restrict__ tn4) {
    const int b = blockIdx.y;
    const float* S  = src   + (size_t)b * 3 * NPTS;
    const float* T  = tgt   + (size_t)b * 3 * NPTS;
    const float* SN = src_n + (size_t)b * 3 * NPTS;
    const float* TN = tgt_n + (size_t)b * 3 * NPTS;
    const float R0 = Rt[b*16+0], R1 = Rt[b*16+1], R2 = Rt[b*16+2];
    const float R3 = Rt[b*16+3], R4 = Rt[b*16+4], R5 = Rt[b*16+5];
    const float R6 = Rt[b*16+6], R7 = Rt[b*16+7], R8 = Rt[b*16+8];
    const float t0 = Rt[b*16+9], t1 = Rt[b*16+10], t2 = Rt[b*16+11];

    const int n0 = blockIdx.x * 512 + threadIdx.x;
    #pragma unroll
    for (int w = 0; w < 2; ++w) {
        const int n = n0 + w * 256;
        float s0 = S[n], s1 = S[NPTS + n], s2 = S[2 * NPTS + n];
        float p0 = R0 * s0 + R1 * s1 + R2 * s2 + t0;
        float p1 = R3 * s0 + R4 * s1 + R5 * s2 + t1;
        float p2 = R6 * s0 + R7 * s1 + R8 * s2 + t2;
        p4[b * NPTS + n] = make_float4(p0, p1, p2, p0 * p0 + p1 * p1 + p2 * p2);

        float q0 = T[n], q1 = T[NPTS + n], q2 = T[2 * NPTS + n];
        q4[b * NPTS + n] = make_float4(q0, q1, q2, q0 * q0 + q1 * q1 + q2 * q2);

        float a0 = SN[n], a1 = SN[NPTS + n], a2 = SN[2 * NPTS + n];
        snr4[b * NPTS + n] = make_float4(R0 * a0 + R1 * a1 + R2 * a2,
                                         R3 * a0 + R4 * a1 + R5 * a2,
                                         R6 * a0 + R7 * a1 + R8 * a2, 0.f);
        float c0 = TN[n], c1 = TN[NPTS + n], c2 = TN[2 * NPTS + n];
        tn4[b * NPTS + n] = make_float4(c0, c1, c2, 0.f);
    }
}

// ---------------- K1: nearest neighbor (both directions) ----------------
// grid (64, B, 2); 512 threads (8 waves). Stage full other-set in LDS with
// .w pre-scaled to -0.5*||q||^2; maximize score s = p.q - 0.5||q||^2
// (argmin d == argmax s). 3 FMA + cmp + 2 cndmask = 6 VALU ops/pair.
// Lanes of a wave share the staged point each iter -> LDS broadcast.
// Stripe ranges ascend in m, so strict-> combine keeps first occurrence.
__global__ void k1_nn(const float4* __restrict__ p4, const float4* __restrict__ q4,
                      float* __restrict__ nnp, int* __restrict__ idxp,
                      float* __restrict__ nnq, int* __restrict__ idxq) {
    const int b = blockIdx.y;
    const int z = blockIdx.z;
    const float4* own = z ? q4 : p4;
    const float4* oth = z ? p4 : q4;
    float* nn = z ? nnq : nnp;
    int* idx = z ? idxq : idxp;

    __shared__ float4 stage[NPTS];  // 64 KB
    const int tid = threadIdx.x;
    for (int i = tid; i < NPTS; i += 512) {
        float4 v = oth[b * NPTS + i];
        v.w *= -0.5f;
        stage[i] = v;
    }

    const int nl = tid & 63;
    const int stripe = tid >> 6;          // 0..7, each scans 512 points
    const int n = blockIdx.x * 64 + nl;
    const float4 p = own[b * NPTS + n];
    __syncthreads();

    const int m0 = stripe << 9;
    float best = -3.4e38f;
    int bi = m0;
    #pragma unroll 8
    for (int m = m0; m < m0 + 512; ++m) {
        float4 q = stage[m];
        float s = fmaf(p.x, q.x, fmaf(p.y, q.y, fmaf(p.z, q.z, q.w)));
        if (s > best) { best = s; bi = m; }
    }
    __syncthreads();

    // reuse stage LDS for the 8-stripe combine
    float* combd = (float*)stage;
    int* combi = (int*)(combd + 512);
    combd[tid] = best;
    combi[tid] = bi;
    __syncthreads();
    if (stripe == 0) {
        for (int s2 = 1; s2 < 8; ++s2) {
            float d2 = combd[s2 * 64 + nl];
            int i2 = combi[s2 * 64 + nl];
            if (d2 > best) { best = d2; bi = i2; }  // ties: lower stripe = lower m wins
        }
        float d = fmaf(-2.0f, best, p.w);
        nn[b * NPTS + n] = sqrtf(fmaxf(d, 0.f) + EPSF);
        idx[b * NPTS + n] = bi;
    }
}

// ---------------- K2: lower median -> tau (exact rank-count select) -----
// grid (64, B, 2); 512 threads. For each element x of the 4096, count
// less = #{o < x}, eq = #{o == x}. x is sorted[2047] iff
// less <= 2047 < less+eq. All winners share the same bit pattern, so
// racing writes are value-identical.
__global__ void k2_tau(const float* __restrict__ nnp, const float* __restrict__ nnq,
                       float* __restrict__ tau) {
    const int b = blockIdx.y;
    const int side = blockIdx.z;
    const float* a = (side ? nnq : nnp) + b * NPTS;
    __shared__ float stage[NPTS];  // 16 KB
    const int tid = threadIdx.x;
    for (int i = tid; i < NPTS; i += 512) stage[i] = a[i];

    const int nl = tid & 63;
    const int stripe = tid >> 6;
    const int n = blockIdx.x * 64 + nl;
    __syncthreads();

    const float x = stage[n];
    int less = 0, eq = 0;
    const int m0 = stripe << 9;
    #pragma unroll 8
    for (int m = m0; m < m0 + 512; ++m) {
        float o = stage[m];  // broadcast read, conflict-free
        less += (o < x) ? 1 : 0;
        eq   += (o == x) ? 1 : 0;
    }
    __syncthreads();

    int* cl = (int*)stage;
    int* ce = cl + 512;
    cl[tid] = less;
    ce[tid] = eq;
    __syncthreads();
    if (stripe == 0) {
        for (int s2 = 1; s2 < 8; ++s2) {
            less += cl[s2 * 64 + nl];
            eq   += ce[s2 * 64 + nl];
        }
        if (less <= 2047 && 2047 < less + eq)
            tau[side * NB + b] = 3.0f * x;
    }
}

// ---------------- K3: incidence weights ---------------------------------
// grid (16, B, 2); 256 threads.
__global__ void k3_w(const float4* __restrict__ snr4, const float4* __restrict__ tn4,
                     const int* __restrict__ idxp, const int* __restrict__ idxq,
                     const float* __restrict__ nnp, const float* __restrict__ nnq,
                     const float* __restrict__ tau,
                     const float* __restrict__ g_q, const float* __restrict__ k_p,
                     const float* __restrict__ k_q, float* __restrict__ out) {
    const int b = blockIdx.y;
    const int z = blockIdx.z;
    const int n = blockIdx.x * 256 + threadIdx.x;
    const float gx = g_q[3 * b + 0], gy = g_q[3 * b + 1], gz = g_q[3 * b + 2];
    const float kp = k_p[b], kq = k_q[b];
    const float keff = kp * kq / (kp + kq + EPSF);

    if (z == 0) {
        float4 sn = snr4[b * NPTS + n];
        float inc = sn.x * gx + sn.y * gy + sn.z * gz;
        int j = idxp[b * NPTS + n];
        float4 tn = tn4[b * NPTS + j];
        float incr = tn.x * gx + tn.y * gy + tn.z * gz;
        float diff = inc - incr;
        float arg = 9.0f - keff * diff * diff;
        float sig = 1.f / (1.f + expf(-arg));
        float geom = (nnp[b * NPTS + n] <= tau[b]) ? 1.f : 0.f;
        out[b * NPTS + n] = sig * geom;
    } else {
        float4 tn = tn4[b * NPTS + n];
        float inc = tn.x * gx + tn.y * gy + tn.z * gz;
        int j = idxq[b * NPTS + n];
        float4 sn = snr4[b * NPTS + j];
        float incr = sn.x * gx + sn.y * gy + sn.z * gz;
        float diff = inc - incr;
        float arg = 9.0f - keff * diff * diff;
        float sig = 1.f / (1.f + expf(-arg));
        float geom = (nnq[b * NPTS + n] <= tau[NB + b]) ? 1.f : 0.f;
        out[NB * NPTS + b * NPTS + n] = sig * geom;
    }
}

extern "C" void kernel_launch(void* const* d_in, const int* in_sizes, int n_in,
                              void* d_out, int out_size, void* d_ws, size_t ws_size,
                              hipStream_t stream) {
    const float* src   = (const float*)d_in[0];
    const float* tgt   = (const float*)d_in[1];
    const float* src_n = (const float*)d_in[2];
    const float* tgt_n = (const float*)d_in[3];
    const float* g_p   = (const float*)d_in[4];
    const float* k_p   = (const float*)d_in[5];
    const float* g_q   = (const float*)d_in[6];
    const float* k_q   = (const float*)d_in[7];
    float* out = (float*)d_out;

    const int BN = NB * NPTS;
    float4* p4   = (float4*)d_ws;
    float4* q4   = p4 + BN;
    float4* snr4 = q4 + BN;
    float4* tn4  = snr4 + BN;
    float* nnp = (float*)(tn4 + BN);
    float* nnq = nnp + BN;
    int* idxp = (int*)(nnq + BN);
    int* idxq = idxp + BN;
    float* tau = (float*)(idxq + BN);   // 2*NB floats
    float* Rt  = tau + 2 * NB;          // NB*16 floats

    k0a_rt<<<dim3(NB), dim3(256), 0, stream>>>(src, tgt, g_p, g_q, Rt);
    k0b_pack<<<dim3(8, NB), dim3(256), 0, stream>>>(src, tgt, src_n, tgt_n, Rt,
                                                    p4, q4, snr4, tn4);
    k1_nn<<<dim3(NPTS / 64, NB, 2), dim3(512), 0, stream>>>(p4, q4, nnp, idxp, nnq, idxq);
    k2_tau<<<dim3(NPTS / 64, NB, 2), dim3(512), 0, stream>>>(nnp, nnq, tau);
    k3_w<<<dim3(NPTS / 256, NB, 2), dim3(256), 0, stream>>>(snr4, tn4, idxp, idxq,
                                                            nnp, nnq, tau,
                                                            g_q, k_p, k_q, out);
}

// Round 5
// 60.343 us; speedup vs baseline: 1.7347x; 1.0193x over previous
//
#include <hip/hip_runtime.h>
#include <math.h>

#define NPTS 4096
#define NB 4
#define EPSF 1e-6f

// ---------------- K0a: per-batch means + gravity-align R, t -------------
// One block per batch (256 threads). Writes Rt[b*16 + {0..8:R, 9..11:t}].
// NOTE (R4 lesson): reduction barriers MUST be full-block __syncthreads;
// raw s_barrier inside `if (tid<256)` desyncs waves (barrier-count
// mismatch) and produced garbage means in R4.
__global__ void k0a_rt(const float* __restrict__ src, const float* __restrict__ tgt,
                       const float* __restrict__ g_p, const float* __restrict__ g_q,
                       float* __restrict__ Rt) {
    const int b = blockIdx.x;
    const int tid = threadIdx.x;
    const float* S = src + (size_t)b * 3 * NPTS;
    const float* T = tgt + (size_t)b * 3 * NPTS;

    float acc[6] = {0.f, 0.f, 0.f, 0.f, 0.f, 0.f};
    for (int n = tid; n < NPTS; n += 256) {
        acc[0] += S[n]; acc[1] += S[NPTS + n]; acc[2] += S[2 * NPTS + n];
        acc[3] += T[n]; acc[4] += T[NPTS + n]; acc[5] += T[2 * NPTS + n];
    }
    __shared__ float red[256];
    __shared__ float sums[6];
    for (int c = 0; c < 6; ++c) {
        red[tid] = acc[c];
        __syncthreads();
        for (int s = 128; s > 0; s >>= 1) {
            if (tid < s) red[tid] += red[tid + s];
            __syncthreads();
        }
        if (tid == 0) sums[c] = red[0];
        __syncthreads();
    }

    if (tid == 0) {
        // gravity_align(g_p[b], g_q[b]) exactly per reference
        float gpx = g_p[3 * b + 0], gpy = g_p[3 * b + 1], gpz = g_p[3 * b + 2];
        float gqx = g_q[3 * b + 0], gqy = g_q[3 * b + 1], gqz = g_q[3 * b + 2];
        float nu = sqrtf(gpx * gpx + gpy * gpy + gpz * gpz);
        float du = fmaxf(nu, EPSF);
        float ux = gpx / du, uy = gpy / du, uz = gpz / du;
        float nv = sqrtf(gqx * gqx + gqy * gqy + gqz * gqz);
        float dv = fmaxf(nv, EPSF);
        float vx = gqx / dv, vy = gqy / dv, vz = gqz / dv;

        float ax = uy * vz - uz * vy;
        float ay = uz * vx - ux * vz;
        float az = ux * vy - uy * vx;
        float an = sqrtf(ax * ax + ay * ay + az * az);
        float dot = ux * vx + uy * vy + uz * vz;
        dot = fminf(1.0f, fmaxf(-1.0f, dot));
        bool parallel = (an < 1e-6f);

        float kx = ax / (an + EPSF), ky = ay / (an + EPSF), kz = az / (an + EPSF);
        float theta = acosf(dot);
        float st = sinf(theta), ct = cosf(theta);

        float K[9] = {0.f, -kz, ky,  kz, 0.f, -kx,  -ky, kx, 0.f};
        float KK[9];
        for (int i = 0; i < 3; ++i)
            for (int j = 0; j < 3; ++j) {
                float s2 = 0.f;
                for (int l = 0; l < 3; ++l) s2 += K[i * 3 + l] * K[l * 3 + j];
                KK[i * 3 + j] = s2;
            }
        float R[9];
        for (int i = 0; i < 9; ++i) {
            float I = (i == 0 || i == 4 || i == 8) ? 1.f : 0.f;
            R[i] = I + st * K[i] + (1.f - ct) * KK[i];
        }
        if (parallel) {
            if (dot < 0.f) {
                float bx, by, bz;
                if (fabsf(ux) < 0.9f) { bx = 1.f; by = 0.f; bz = 0.f; }
                else                  { bx = 0.f; by = 1.f; bz = 0.f; }
                float cx = uy * bz - uz * by;
                float cy = uz * bx - ux * bz;
                float cz = ux * by - uy * bx;
                float cn = sqrtf(cx * cx + cy * cy + cz * cz);
                float cd = fmaxf(cn, EPSF);
                cx /= cd; cy /= cd; cz /= cd;
                float K2[9] = {0.f, -cz, cy,  cz, 0.f, -cx,  -cy, cx, 0.f};
                float K2K2[9];
                for (int i = 0; i < 3; ++i)
                    for (int j = 0; j < 3; ++j) {
                        float s2 = 0.f;
                        for (int l = 0; l < 3; ++l) s2 += K2[i * 3 + l] * K2[l * 3 + j];
                        K2K2[i * 3 + j] = s2;
                    }
                for (int i = 0; i < 9; ++i) {
                    float I = (i == 0 || i == 4 || i == 8) ? 1.f : 0.f;
                    R[i] = I + 2.f * K2K2[i];
                }
            } else if (dot > 0.f) {
                for (int i = 0; i < 9; ++i) R[i] = (i == 0 || i == 4 || i == 8) ? 1.f : 0.f;
            }
        }
        float ms0 = sums[0] / (float)NPTS, ms1 = sums[1] / (float)NPTS, ms2 = sums[2] / (float)NPTS;
        float mt0 = sums[3] / (float)NPTS, mt1 = sums[4] / (float)NPTS, mt2 = sums[5] / (float)NPTS;
        for (int i = 0; i < 9; ++i) Rt[b * 16 + i] = R[i];
        Rt[b * 16 + 9]  = mt0 - (R[0] * ms0 + R[1] * ms1 + R[2] * ms2);
        Rt[b * 16 + 10] = mt1 - (R[3] * ms0 + R[4] * ms1 + R[5] * ms2);
        Rt[b * 16 + 11] = mt2 - (R[6] * ms0 + R[7] * ms1 + R[8] * ms2);
    }
}

// ---------------- K0b: transform + pack float4 --------------------------
// grid (8, NB); 256 threads; each thread handles 2 points.
__global__ void k0b_pack(const float* __restrict__ src, const float* __restrict__ tgt,
                         const float* __restrict__ src_n, const float* __restrict__ tgt_n,
                         const float* __restrict__ Rt,
                         float4* __restrict__ p4, float4* __restrict__ q4,
                         float4* __restrict__ snr4, float4* __restrict__ tn4) {
    const int b = blockIdx.y;
    const float* S  = src   + (size_t)b * 3 * NPTS;
    const float* T  = tgt   + (size_t)b * 3 * NPTS;
    const float* SN = src_n + (size_t)b * 3 * NPTS;
    const float* TN = tgt_n + (size_t)b * 3 * NPTS;
    const float R0 = Rt[b*16+0], R1 = Rt[b*16+1], R2 = Rt[b*16+2];
    const float R3 = Rt[b*16+3], R4 = Rt[b*16+4], R5 = Rt[b*16+5];
    const float R6 = Rt[b*16+6], R7 = Rt[b*16+7], R8 = Rt[b*16+8];
    const float t0 = Rt[b*16+9], t1 = Rt[b*16+10], t2 = Rt[b*16+11];

    const int n0 = blockIdx.x * 512 + threadIdx.x;
    #pragma unroll
    for (int w = 0; w < 2; ++w) {
        const int n = n0 + w * 256;
        float s0 = S[n], s1 = S[NPTS + n], s2 = S[2 * NPTS + n];
        float p0 = R0 * s0 + R1 * s1 + R2 * s2 + t0;
        float p1 = R3 * s0 + R4 * s1 + R5 * s2 + t1;
        float p2 = R6 * s0 + R7 * s1 + R8 * s2 + t2;
        p4[b * NPTS + n] = make_float4(p0, p1, p2, p0 * p0 + p1 * p1 + p2 * p2);

        float q0 = T[n], q1 = T[NPTS + n], q2 = T[2 * NPTS + n];
        q4[b * NPTS + n] = make_float4(q0, q1, q2, q0 * q0 + q1 * q1 + q2 * q2);

        float a0 = SN[n], a1 = SN[NPTS + n], a2 = SN[2 * NPTS + n];
        snr4[b * NPTS + n] = make_float4(R0 * a0 + R1 * a1 + R2 * a2,
                                         R3 * a0 + R4 * a1 + R5 * a2,
                                         R6 * a0 + R7 * a1 + R8 * a2, 0.f);
        float c0 = TN[n], c1 = TN[NPTS + n], c2 = TN[2 * NPTS + n];
        tn4[b * NPTS + n] = make_float4(c0, c1, c2, 0.f);
    }
}

// ---------------- K1: nearest neighbor (both directions) ----------------
// grid (64, B, 2); 1024 threads (16 waves; 2 blocks/CU -> 32 waves/CU).
// Stage full other-set in LDS with .w pre-scaled to -0.5*||q||^2;
// maximize score s = p.q - 0.5||q||^2 (argmin d == argmax s).
// 3 FMA + cmp + 2 cndmask = 6 VALU ops/pair; LDS reads are broadcast.
// 16 stripes x 256 m, ascending; strict > keeps first occurrence.
__global__ void k1_nn(const float4* __restrict__ p4, const float4* __restrict__ q4,
                      float* __restrict__ nnp, int* __restrict__ idxp,
                      float* __restrict__ nnq, int* __restrict__ idxq) {
    const int b = blockIdx.y;
    const int z = blockIdx.z;
    const float4* own = z ? q4 : p4;
    const float4* oth = z ? p4 : q4;
    float* nn = z ? nnq : nnp;
    int* idx = z ? idxq : idxp;

    __shared__ float4 stage[NPTS];  // 64 KB
    const int tid = threadIdx.x;
    for (int i = tid; i < NPTS; i += 1024) {
        float4 v = oth[b * NPTS + i];
        v.w *= -0.5f;
        stage[i] = v;
    }

    const int nl = tid & 63;
    const int stripe = tid >> 6;          // 0..15, each scans 256 points
    const int n = blockIdx.x * 64 + nl;
    const float4 p = own[b * NPTS + n];
    __syncthreads();

    const int m0 = stripe << 8;
    float best = -3.4e38f;
    int bi = m0;
    #pragma unroll 8
    for (int m = m0; m < m0 + 256; ++m) {
        float4 q = stage[m];
        float s = fmaf(p.x, q.x, fmaf(p.y, q.y, fmaf(p.z, q.z, q.w)));
        if (s > best) { best = s; bi = m; }
    }
    __syncthreads();

    // reuse stage LDS for the 16-stripe combine
    float* combd = (float*)stage;
    int* combi = (int*)(combd + 1024);
    combd[tid] = best;
    combi[tid] = bi;
    __syncthreads();
    if (stripe == 0) {
        for (int s2 = 1; s2 < 16; ++s2) {
            float d2 = combd[s2 * 64 + nl];
            int i2 = combi[s2 * 64 + nl];
            if (d2 > best) { best = d2; bi = i2; }  // ties: lower stripe = lower m wins
        }
        float d = fmaf(-2.0f, best, p.w);
        nn[b * NPTS + n] = sqrtf(fmaxf(d, 0.f) + EPSF);
        idx[b * NPTS + n] = bi;
    }
}

// ---------------- K2: lower median -> tau (exact rank-count select) -----
// grid (64, B, 2); 1024 threads. For each element x of the 4096, count
// less = #{o < x}, eq = #{o == x}. x is sorted[2047] iff
// less <= 2047 < less+eq. All winners share the same bit pattern, so
// racing writes are value-identical.
__global__ void k2_tau(const float* __restrict__ nnp, const float* __restrict__ nnq,
                       float* __restrict__ tau) {
    const int b = blockIdx.y;
    const int side = blockIdx.z;
    const float* a = (side ? nnq : nnp) + b * NPTS;
    __shared__ float stage[NPTS];  // 16 KB
    const int tid = threadIdx.x;
    for (int i = tid; i < NPTS; i += 1024) stage[i] = a[i];

    const int nl = tid & 63;
    const int stripe = tid >> 6;          // 0..15, each scans 256
    const int n = blockIdx.x * 64 + nl;
    __syncthreads();

    const float x = stage[n];
    int less = 0, eq = 0;
    const int m0 = stripe << 8;
    #pragma unroll 8
    for (int m = m0; m < m0 + 256; ++m) {
        float o = stage[m];  // broadcast read, conflict-free
        less += (o < x) ? 1 : 0;
        eq   += (o == x) ? 1 : 0;
    }
    __syncthreads();

    int* cl = (int*)stage;
    int* ce = cl + 1024;
    cl[tid] = less;
    ce[tid] = eq;
    __syncthreads();
    if (stripe == 0) {
        for (int s2 = 1; s2 < 16; ++s2) {
            less += cl[s2 * 64 + nl];
            eq   += ce[s2 * 64 + nl];
        }
        if (less <= 2047 && 2047 < less + eq)
            tau[side * NB + b] = 3.0f * x;
    }
}

// ---------------- K3: incidence weights ---------------------------------
// grid (16, B, 2); 256 threads.
__global__ void k3_w(const float4* __restrict__ snr4, const float4* __restrict__ tn4,
                     const int* __restrict__ idxp, const int* __restrict__ idxq,
                     const float* __restrict__ nnp, const float* __restrict__ nnq,
                     const float* __restrict__ tau,
                     const float* __restrict__ g_q, const float* __restrict__ k_p,
                     const float* __restrict__ k_q, float* __restrict__ out) {
    const int b = blockIdx.y;
    const int z = blockIdx.z;
    const int n = blockIdx.x * 256 + threadIdx.x;
    const float gx = g_q[3 * b + 0], gy = g_q[3 * b + 1], gz = g_q[3 * b + 2];
    const float kp = k_p[b], kq = k_q[b];
    const float keff = kp * kq / (kp + kq + EPSF);

    if (z == 0) {
        float4 sn = snr4[b * NPTS + n];
        float inc = sn.x * gx + sn.y * gy + sn.z * gz;
        int j = idxp[b * NPTS + n];
        float4 tn = tn4[b * NPTS + j];
        float incr = tn.x * gx + tn.y * gy + tn.z * gz;
        float diff = inc - incr;
        float arg = 9.0f - keff * diff * diff;
        float sig = 1.f / (1.f + expf(-arg));
        float geom = (nnp[b * NPTS + n] <= tau[b]) ? 1.f : 0.f;
        out[b * NPTS + n] = sig * geom;
    } else {
        float4 tn = tn4[b * NPTS + n];
        float inc = tn.x * gx + tn.y * gy + tn.z * gz;
        int j = idxq[b * NPTS + n];
        float4 sn = snr4[b * NPTS + j];
        float incr = sn.x * gx + sn.y * gy + sn.z * gz;
        float diff = inc - incr;
        float arg = 9.0f - keff * diff * diff;
        float sig = 1.f / (1.f + expf(-arg));
        float geom = (nnq[b * NPTS + n] <= tau[NB + b]) ? 1.f : 0.f;
        out[NB * NPTS + b * NPTS + n] = sig * geom;
    }
}

extern "C" void kernel_launch(void* const* d_in, const int* in_sizes, int n_in,
                              void* d_out, int out_size, void* d_ws, size_t ws_size,
                              hipStream_t stream) {
    const float* src   = (const float*)d_in[0];
    const float* tgt   = (const float*)d_in[1];
    const float* src_n = (const float*)d_in[2];
    const float* tgt_n = (const float*)d_in[3];
    const float* g_p   = (const float*)d_in[4];
    const float* k_p   = (const float*)d_in[5];
    const float* g_q   = (const float*)d_in[6];
    const float* k_q   = (const float*)d_in[7];
    float* out = (float*)d_out;

    const int BN = NB * NPTS;
    float4* p4   = (float4*)d_ws;
    float4* q4   = p4 + BN;
    float4* snr4 = q4 + BN;
    float4* tn4  = snr4 + BN;
    float* nnp = (float*)(tn4 + BN);
    float* nnq = nnp + BN;
    int* idxp = (int*)(nnq + BN);
    int* idxq = idxp + BN;
    float* tau = (float*)(idxq + BN);   // 2*NB floats
    float* Rt  = tau + 2 * NB;          // NB*16 floats

    k0a_rt<<<dim3(NB), dim3(256), 0, stream>>>(src, tgt, g_p, g_q, Rt);
    k0b_pack<<<dim3(8, NB), dim3(256), 0, stream>>>(src, tgt, src_n, tgt_n, Rt,
                                                    p4, q4, snr4, tn4);
    k1_nn<<<dim3(NPTS / 64, NB, 2), dim3(1024), 0, stream>>>(p4, q4, nnp, idxp, nnq, idxq);
    k2_tau<<<dim3(NPTS / 64, NB, 2), dim3(1024), 0, stream>>>(nnp, nnq, tau);
    k3_w<<<dim3(NPTS / 256, NB, 2), dim3(256), 0, stream>>>(snr4, tn4, idxp, idxq,
                                                            nnp, nnq, tau,
                                                            g_q, k_p, k_q, out);
}